// Round 2
// baseline (259.187 us; speedup 1.0000x reference)
//
#include <hip/hip_runtime.h>
#include <hip/hip_bf16.h>

#define VDIM 50257
#define EDIM 128
#define MROWS 2048
#define KMAIN 50240            // 1570 * 32; tail of 17 handled in fp32 in k_reduce
#define KTAIL 17               // VDIM - KMAIN
#define STEPS_TOTAL 1570
#define SPLIT 32
#define BM 128

using short8_t = __attribute__((ext_vector_type(8))) short;
using float4_t = __attribute__((ext_vector_type(4))) float;

static __device__ __forceinline__ short f2bf(float f) {
    union { __hip_bfloat16 h; short s; } u;
    u.h = __float2bfloat16(f);
    return u.s;
}

static __device__ __forceinline__ unsigned pack_bf2(float lo, float hi) {
    unsigned l = (unsigned short)f2bf(lo);
    unsigned h = (unsigned short)f2bf(hi);
    return l | (h << 16);
}

// W (VDIM x EDIM fp32, row-major) -> Wt (EDIM x KMAIN bf16, row-major).
__global__ __launch_bounds__(256) void k_transpose(const float* __restrict__ W,
                                                   short* __restrict__ Wt) {
    __shared__ float tile[64][132];   // +4 pad: transposed reads spread banks
    const int t = threadIdx.x;
    const int v0 = blockIdx.x * 64;   // KMAIN/64 = 785 blocks, exact
    #pragma unroll
    for (int p = 0; p < 32; ++p) {
        int idx = p * 256 + t;
        int r = idx >> 7, c = idx & 127;
        tile[r][c] = W[(size_t)(v0 + r) * EDIM + c];
    }
    __syncthreads();
    const int e = t >> 1, half = t & 1;
    short* dst = Wt + (size_t)e * KMAIN + v0 + half * 32;  // 16B aligned
    #pragma unroll
    for (int i = 0; i < 4; ++i) {
        short8_t pk;
        #pragma unroll
        for (int j = 0; j < 8; ++j) pk[j] = f2bf(tile[half * 32 + i * 8 + j][e]);
        *reinterpret_cast<short8_t*>(dst + i * 8) = pk;
    }
}

// Split-K bf16 MFMA GEMM with LDS-staged, coalesced A loads.
// Grid = 16 M-tiles * SPLIT = 512 blocks of 256 threads (2 blocks/CU).
// bid = s + SPLIT*mt -> same-split blocks share an XCD (bid%8 == s%8) so the
// 400 KB Wt chunk is L2-resident per XCD.
// Per step: stage A[128 rows][32 k] fp32 -> bf16 into LDS (double-buffered),
// each wave computes a 32x128 tile via 16x16x32 MFMA.
__global__ __launch_bounds__(256, 2) void k_main(const float* __restrict__ A,
                                                 const short* __restrict__ Wt,
                                                 float* __restrict__ P) {
    __shared__ short ldsA[2][BM][32];   // 16 KB total, unpadded (b128 reads are even)

    const int bid  = blockIdx.x;
    const int s    = bid & (SPLIT - 1);
    const int mt   = bid >> 5;
    const int t    = threadIdx.x;
    const int lane = t & 63;
    const int wv   = t >> 6;

    // balanced split: 49 or 50 steps per chunk
    const int step0  = (s * STEPS_TOTAL) / SPLIT;
    const int step1  = ((s + 1) * STEPS_TOTAL) / SPLIT;
    const int nsteps = step1 - step0;
    const int k0     = step0 * 32;

    // --- staging identity: thread covers rows (t>>4)+16p, dwords 2*jj, 2*jj+1
    const int jj = t & 15;
    const int r0 = t >> 4;
    const float* arow[8];
    #pragma unroll
    for (int p = 0; p < 8; ++p)
        arow[p] = A + (size_t)(mt * BM + r0 + 16 * p) * VDIM + k0 + 2 * jj;

    // --- fragment identity
    const int rl = lane & 15;
    const int kg = lane >> 4;

    const short* wrow[8];
    #pragma unroll
    for (int cf = 0; cf < 8; ++cf)
        wrow[cf] = Wt + (size_t)(cf * 16 + rl) * KMAIN + k0 + kg * 8;

    float4_t acc[2][8];
    #pragma unroll
    for (int i = 0; i < 2; ++i)
        #pragma unroll
        for (int j = 0; j < 8; ++j) acc[i][j] = (float4_t){0.f, 0.f, 0.f, 0.f};

    auto do_step = [&](int c) {
        short8_t bw[8];
        #pragma unroll
        for (int cf = 0; cf < 8; ++cf) {
            bw[cf] = *reinterpret_cast<const short8_t*>(wrow[cf]);  // 16B, L1-hot
            wrow[cf] += 32;
        }
        short8_t af0 = *reinterpret_cast<const short8_t*>(&ldsA[c][wv * 32 + rl][kg * 8]);
        short8_t af1 = *reinterpret_cast<const short8_t*>(&ldsA[c][wv * 32 + 16 + rl][kg * 8]);
        #pragma unroll
        for (int cf = 0; cf < 8; ++cf) {
            acc[0][cf] = __builtin_amdgcn_mfma_f32_16x16x32_bf16(af0, bw[cf], acc[0][cf], 0, 0, 0);
            acc[1][cf] = __builtin_amdgcn_mfma_f32_16x16x32_bf16(af1, bw[cf], acc[1][cf], 0, 0, 0);
        }
    };

    // prologue: stage step 0 into buf 0
    #pragma unroll
    for (int p = 0; p < 8; ++p) {
        float x0 = arow[p][0], x1 = arow[p][1];
        *reinterpret_cast<unsigned*>(&ldsA[0][r0 + 16 * p][2 * jj]) = pack_bf2(x0, x1);
        arow[p] += 32;
    }
    __syncthreads();

    int cur = 0;
    for (int it = 0; it < nsteps - 1; ++it) {
        // issue next-step A loads early (latency hides under MFMA)
        float x0[8], x1[8];
        #pragma unroll
        for (int p = 0; p < 8; ++p) {
            x0[p] = arow[p][0];
            x1[p] = arow[p][1];
            arow[p] += 32;
        }
        do_step(cur);
        #pragma unroll
        for (int p = 0; p < 8; ++p)
            *reinterpret_cast<unsigned*>(&ldsA[cur ^ 1][r0 + 16 * p][2 * jj]) =
                pack_bf2(x0[p], x1[p]);
        __syncthreads();
        cur ^= 1;
    }
    do_step(cur);

    // Partial write: C/D layout col = lane&15, row = (lane>>4)*4 + j  [m89-verified]
    float* pout = P + ((size_t)s * MROWS + (size_t)mt * BM + (size_t)wv * 32) * EDIM;
    #pragma unroll
    for (int rf = 0; rf < 2; ++rf)
        #pragma unroll
        for (int cf = 0; cf < 8; ++cf)
            #pragma unroll
            for (int j = 0; j < 4; ++j) {
                int rr = rf * 16 + kg * 4 + j;
                int cc = cf * 16 + rl;
                pout[(size_t)rr * EDIM + cc] = acc[rf][cf][j];
            }
}

// out = bias + sum of SPLIT partials + fp32 K-tail, float4-vectorized.
__global__ __launch_bounds__(256) void k_reduce(const float* __restrict__ P,
                                                const float* __restrict__ A,
                                                const float* __restrict__ W,
                                                const float* __restrict__ bias,
                                                float* __restrict__ out) {
    const int i4 = blockIdx.x * 256 + threadIdx.x;   // float4 index, 65536 total
    const int m  = i4 >> 5;                          // 32 float4 per output row
    const int e4 = i4 & 31;
    float4_t acc = reinterpret_cast<const float4_t*>(bias)[e4];
    #pragma unroll
    for (int j = 0; j < KTAIL; ++j) {
        float a = A[(size_t)m * VDIM + KMAIN + j];
        float4_t w = reinterpret_cast<const float4_t*>(W + (size_t)(KMAIN + j) * EDIM)[e4];
        acc += a * w;
    }
    float4_t ps = {0.f, 0.f, 0.f, 0.f};
    #pragma unroll
    for (int p = 0; p < SPLIT; ++p)
        ps += reinterpret_cast<const float4_t*>(P)[(size_t)p * (MROWS * EDIM / 4) + i4];
    acc += ps;
    reinterpret_cast<float4_t*>(out)[i4] = acc;
}

// Emergency fallback if workspace is too small: plain fp32, deterministic.
__global__ __launch_bounds__(256) void k_naive(const float* __restrict__ A,
                                               const float* __restrict__ W,
                                               const float* __restrict__ bias,
                                               float* __restrict__ out) {
    const int e  = threadIdx.x & 127;
    const int mi = threadIdx.x >> 7;
    const int m0 = blockIdx.x * 8 + mi;
    float acc[4] = {0.f, 0.f, 0.f, 0.f};
    for (int k = 0; k < VDIM; ++k) {
        float w = W[(size_t)k * EDIM + e];
        #pragma unroll
        for (int q = 0; q < 4; ++q)
            acc[q] += A[(size_t)(m0 + q * 2) * VDIM + k] * w;
    }
    #pragma unroll
    for (int q = 0; q < 4; ++q)
        out[(size_t)(m0 + q * 2) * EDIM + e] = acc[q] + bias[e];
}

extern "C" void kernel_launch(void* const* d_in, const int* in_sizes, int n_in,
                              void* d_out, int out_size, void* d_ws, size_t ws_size,
                              hipStream_t stream) {
    const float* A    = (const float*)d_in[0];  // (16,128,50257) fp32
    const float* W    = (const float*)d_in[1];  // (50257,128) fp32
    const float* bias = (const float*)d_in[2];  // (128,) fp32
    float* out = (float*)d_out;                 // (16,128,128) fp32

    const size_t WT_BYTES = (size_t)EDIM * KMAIN * sizeof(short);          // 12.86 MB
    const size_t P_BYTES  = (size_t)SPLIT * MROWS * EDIM * sizeof(float);  // 33.55 MB

    if (ws_size >= WT_BYTES + P_BYTES) {
        short* Wt = (short*)d_ws;
        float* P  = (float*)((char*)d_ws + WT_BYTES);
        k_transpose<<<KMAIN / 64, 256, 0, stream>>>(W, Wt);
        k_main<<<(MROWS / BM) * SPLIT, 256, 0, stream>>>(A, Wt, P);
        k_reduce<<<(MROWS * EDIM) / (256 * 4), 256, 0, stream>>>(P, A, W, bias, out);
    } else {
        k_naive<<<MROWS / 8, 256, 0, stream>>>(A, W, bias, out);
    }
}

// Round 3
// 137.403 us; speedup vs baseline: 1.8863x; 1.8863x over previous
//
#include <hip/hip_runtime.h>
#include <hip/hip_bf16.h>

#define VDIM 50257
#define EDIM 128
#define MROWS 2048
#define KMAIN 50240            // 1570 k-steps of 32; tail of 17 in fp32 in k_reduce
#define KTAIL 17               // VDIM - KMAIN
#define KSTEPS 1570
#define SPLIT 32
#define BM 128

using short8_t = __attribute__((ext_vector_type(8))) short;
using float4_t = __attribute__((ext_vector_type(4))) float;

static __device__ __forceinline__ short f2bf(float f) {
    union { __hip_bfloat16 h; short s; } u;
    u.h = __float2bfloat16(f);
    return u.s;
}

static __device__ __forceinline__ unsigned pack_bf2(float lo, float hi) {
    unsigned l = (unsigned short)f2bf(lo);
    unsigned h = (unsigned short)f2bf(hi);
    return l | (h << 16);
}

// W (VDIM x EDIM fp32) -> Wt2[step][128 e][32 k] bf16, step-tiled so each
// 8 KB B-tile is contiguous (sequential reads in k_main).
__global__ __launch_bounds__(256) void k_wt2(const float* __restrict__ W,
                                             short* __restrict__ Wt2) {
    __shared__ float tile[32][132];             // +4 pad for column reads
    const int t = threadIdx.x;
    const int step = blockIdx.x;                // 0..1569
    const float* src = W + (size_t)step * 4096; // 32 rows x 128 e, contiguous
    #pragma unroll
    for (int p = 0; p < 16; ++p) {
        int idx = p * 256 + t;
        tile[idx >> 7][idx & 127] = src[idx];
    }
    __syncthreads();
    const int e = t >> 1, half = t & 1;
    short* dst = Wt2 + (size_t)step * 4096 + e * 32 + half * 16;
    #pragma unroll
    for (int q = 0; q < 2; ++q) {
        short8_t pk;
        #pragma unroll
        for (int i = 0; i < 8; ++i) pk[i] = f2bf(tile[half * 16 + q * 8 + i][e]);
        *reinterpret_cast<short8_t*>(dst + q * 8) = pk;
    }
}

// Split-K bf16 MFMA GEMM, BK=128 superstep (512 B contiguous per row-visit for
// DRAM page-hit amortization), double-buffered LDS, one barrier per superstep.
// Grid 512 = 16 mt x 32 s, 2 blocks/CU. XCD-grouped: xcd=bid&7 handles 4 s-values.
__global__ __launch_bounds__(256, 2) void k_main(const float* __restrict__ A,
                                                 const short* __restrict__ Wt2,
                                                 float* __restrict__ P) {
    // row stride 136 shorts = 272 B = 17*16 B: 16B-aligned rows, and 272/4=68
    // dwords/row makes bank-quads uniform for b128 frags (17*row mod 8 = row mod 8).
    __shared__ short tile[2][BM][136];          // 69632 B total

    const int bid = blockIdx.x;
    const int xcd = bid & 7, idx = bid >> 3;    // same-s blocks share an XCD (L2 Wt2 reuse)
    const int s  = xcd + 8 * (idx >> 4);
    const int mt = idx & 15;

    const int t = threadIdx.x, w = t >> 6, l = t & 63;

    // balanced: splits 0,1 get 50 k-steps, rest 49. 13 supersteps, last has 1-2 inner.
    const int start_step = 49 * s + (s < 2 ? s : 2);
    const int lastn      = (s < 2) ? 2 : 1;
    const size_t kb      = (size_t)start_step * 32;

    // staging identities: chunk = 128 rows x 32 k fp32 of the NEXT superstep.
    // instr granularity: 4 rows x 16 lanes x 4B (64 B/row contiguous -> ~8 lines/instr)
    const int srow_lo = w * 32 + ((l >> 2) & 15);   // + rowblk*16
    const float* aRow0 = A + (size_t)(mt * BM + srow_lo) * VDIM + kb + (l & 3) * 4;
    const float* aRow1 = aRow0 + (size_t)16 * VDIM;

    // fragment identities
    const int rl = l & 15, kg = l >> 4;
    char* const ldsbase = (char*)&tile[0][0][0];
    const int fr0 = (w * 32 + rl) * 272 + kg * 16;      // af0 byte offset
    const int fr1 = fr0 + 16 * 272;                      // af1
    const int swb = srow_lo * 272 + (l & 3) * 8;         // stage write base (rowblk,win,j added)

    float4_t acc[2][8];
    #pragma unroll
    for (int i = 0; i < 2; ++i)
        #pragma unroll
        for (int j = 0; j < 8; ++j) acc[i][j] = (float4_t){0.f, 0.f, 0.f, 0.f};

    float f[4][4];

    auto stage_load = [&](int kss, int j) {
        #pragma unroll
        for (int g = 0; g < 4; ++g) {
            const int rowblk = g & 1, win = g >> 1;
            const float* ap = (rowblk ? aRow1 : aRow0) + kss + j * 32 + win * 16;
            #pragma unroll
            for (int i = 0; i < 4; ++i) f[g][i] = ap[i];
        }
    };
    auto stage_write = [&](int buf, int j) {
        #pragma unroll
        for (int g = 0; g < 4; ++g) {
            const int rowblk = g & 1, win = g >> 1;
            uint2 v;
            v.x = pack_bf2(f[g][0], f[g][1]);
            v.y = pack_bf2(f[g][2], f[g][3]);
            *reinterpret_cast<uint2*>(ldsbase + buf * 34816 + swb + rowblk * (16 * 272)
                                      + j * 64 + win * 32) = v;
        }
    };
    auto compute_inner = [&](int buf, int step, int j) {
        const short* bbase = Wt2 + (size_t)step * 4096 + rl * 32 + kg * 8;
        short8_t bw[8];
        #pragma unroll
        for (int cf = 0; cf < 8; ++cf)
            bw[cf] = *reinterpret_cast<const short8_t*>(bbase + cf * 512); // 1KB contig/instr
        short8_t af0 = *reinterpret_cast<const short8_t*>(ldsbase + buf * 34816 + fr0 + j * 64);
        short8_t af1 = *reinterpret_cast<const short8_t*>(ldsbase + buf * 34816 + fr1 + j * 64);
        #pragma unroll
        for (int cf = 0; cf < 8; ++cf) {
            acc[0][cf] = __builtin_amdgcn_mfma_f32_16x16x32_bf16(af0, bw[cf], acc[0][cf], 0, 0, 0);
            acc[1][cf] = __builtin_amdgcn_mfma_f32_16x16x32_bf16(af1, bw[cf], acc[1][cf], 0, 0, 0);
        }
    };

    // prologue: stage superstep 0 into buf 0
    #pragma unroll
    for (int j = 0; j < 4; ++j) { stage_load(0, j); stage_write(0, j); }
    __syncthreads();

    const int NSS = 13;
    for (int ss = 0; ss < NSS; ++ss) {
        const int cur  = ss & 1;
        const int curn = (ss < 12) ? 4 : lastn;
        const int nxtn = (ss < 11) ? 4 : ((ss == 11) ? lastn : 0);
        const int step0 = start_step + ss * 4;
        #pragma unroll
        for (int j = 0; j < 4; ++j) {
            if (j < nxtn) stage_load((ss + 1) * 128, j);      // issue early (T14)
            if (j < curn) compute_inner(cur, step0 + j, j);   // hides load latency
            if (j < nxtn) stage_write(cur ^ 1, j);
        }
        __syncthreads();
    }

    // Partial write: C/D layout col = lane&15, row = (lane>>4)*4 + j  [m89-verified]
    float* pout = P + ((size_t)s * MROWS + (size_t)mt * BM + (size_t)w * 32) * EDIM;
    #pragma unroll
    for (int rf = 0; rf < 2; ++rf)
        #pragma unroll
        for (int cf = 0; cf < 8; ++cf)
            #pragma unroll
            for (int j = 0; j < 4; ++j) {
                int rr = rf * 16 + kg * 4 + j;
                int cc = cf * 16 + rl;
                pout[(size_t)rr * EDIM + cc] = acc[rf][cf][j];
            }
}

// out = bias + sum of SPLIT partials + fp32 K-tail, float4-vectorized.
__global__ __launch_bounds__(256) void k_reduce(const float* __restrict__ P,
                                                const float* __restrict__ A,
                                                const float* __restrict__ W,
                                                const float* __restrict__ bias,
                                                float* __restrict__ out) {
    const int i4 = blockIdx.x * 256 + threadIdx.x;   // float4 index, 65536 total
    const int m  = i4 >> 5;                          // 32 float4 per output row
    const int e4 = i4 & 31;
    float4_t acc = reinterpret_cast<const float4_t*>(bias)[e4];
    #pragma unroll
    for (int j = 0; j < KTAIL; ++j) {
        float a = A[(size_t)m * VDIM + KMAIN + j];
        float4_t w = reinterpret_cast<const float4_t*>(W + (size_t)(KMAIN + j) * EDIM)[e4];
        acc += a * w;
    }
    float4_t ps = {0.f, 0.f, 0.f, 0.f};
    #pragma unroll
    for (int p = 0; p < SPLIT; ++p)
        ps += reinterpret_cast<const float4_t*>(P)[(size_t)p * (MROWS * EDIM / 4) + i4];
    acc += ps;
    reinterpret_cast<float4_t*>(out)[i4] = acc;
}

// Emergency fallback if workspace is too small: plain fp32, deterministic.
__global__ __launch_bounds__(256) void k_naive(const float* __restrict__ A,
                                               const float* __restrict__ W,
                                               const float* __restrict__ bias,
                                               float* __restrict__ out) {
    const int e  = threadIdx.x & 127;
    const int mi = threadIdx.x >> 7;
    const int m0 = blockIdx.x * 8 + mi;
    float acc[4] = {0.f, 0.f, 0.f, 0.f};
    for (int k = 0; k < VDIM; ++k) {
        float w = W[(size_t)k * EDIM + e];
        #pragma unroll
        for (int q = 0; q < 4; ++q)
            acc[q] += A[(size_t)(m0 + q * 2) * VDIM + k] * w;
    }
    #pragma unroll
    for (int q = 0; q < 4; ++q)
        out[(size_t)(m0 + q * 2) * EDIM + e] = acc[q] + bias[e];
}

extern "C" void kernel_launch(void* const* d_in, const int* in_sizes, int n_in,
                              void* d_out, int out_size, void* d_ws, size_t ws_size,
                              hipStream_t stream) {
    const float* A    = (const float*)d_in[0];  // (16,128,50257) fp32
    const float* W    = (const float*)d_in[1];  // (50257,128) fp32
    const float* bias = (const float*)d_in[2];  // (128,) fp32
    float* out = (float*)d_out;                 // (16,128,128) fp32

    const size_t WT2_BYTES = (size_t)KSTEPS * 4096 * sizeof(short);         // 12.86 MB
    const size_t P_BYTES   = (size_t)SPLIT * MROWS * EDIM * sizeof(float);  // 33.55 MB

    if (ws_size >= WT2_BYTES + P_BYTES) {
        short* Wt2 = (short*)d_ws;
        float* P   = (float*)((char*)d_ws + WT2_BYTES);
        k_wt2<<<KSTEPS, 256, 0, stream>>>(W, Wt2);
        k_main<<<512, 256, 0, stream>>>(A, Wt2, P);
        k_reduce<<<(MROWS * EDIM) / (256 * 4), 256, 0, stream>>>(P, A, W, bias, out);
    } else {
        k_naive<<<MROWS / 8, 256, 0, stream>>>(A, W, bias, out);
    }
}